// Round 11
// baseline (326.144 us; speedup 1.0000x reference)
//
#include <hip/hip_runtime.h>

// ---------------------------------------------------------------------------
// GIN 2-layer forward. R11: barrier-free MLP — A/B MFMA fragments loaded
// per-k-iter straight from global (L2-hot) into VGPRs; no LDS staging, no
// k-loop barriers (compiler vmcnt-pipelines). Only the 64x264 T tile lives
// in LDS (1 barrier/block). R10 agg + single-kernel scan + prep unchanged.
// N=50000, E=600000, dims 128->256->256->256->128.
// ---------------------------------------------------------------------------

typedef __bf16 bf16x8 __attribute__((ext_vector_type(8)));
typedef float f32x4 __attribute__((ext_vector_type(4)));
typedef float f32x2 __attribute__((ext_vector_type(2)));
typedef unsigned short u16x4 __attribute__((ext_vector_type(4)));
typedef unsigned short u16x8 __attribute__((ext_vector_type(8)));
typedef unsigned int uint32;
typedef uint32 u32x4 __attribute__((ext_vector_type(4)));

__device__ __forceinline__ unsigned short f2bf(float f) {
  uint32 u = __builtin_bit_cast(uint32, f);
  u += 0x7FFFu + ((u >> 16) & 1u);  // RNE
  return (unsigned short)(u >> 16);
}
__device__ __forceinline__ f32x2 bfpair(uint32 w) {
  f32x2 r;
  r.x = __builtin_bit_cast(float, w << 16);
  r.y = __builtin_bit_cast(float, w & 0xFFFF0000u);
  return r;
}

// ---------------------------- CSR build ------------------------------------
__global__ void hist(const int* __restrict__ eidx, int* __restrict__ deg, int E) {
  int e = blockIdx.x * blockDim.x + threadIdx.x;
  if (e < E) atomicAdd(&deg[eidx[e + E]], 1);
}

// Single-kernel exclusive scan (all 196 blocks co-resident). flg pre-zeroed.
__global__ __launch_bounds__(256) void scan_all(
    const int* __restrict__ deg, int* __restrict__ offs, int* __restrict__ pos,
    int* __restrict__ aggr, int* __restrict__ incl, int* __restrict__ flg,
    int Nn, int nb) {
  __shared__ int sm[256];
  __shared__ int s_prefix;
  const int t = threadIdx.x;
  const int b = blockIdx.x;
  const int i = b * 256 + t;
  int v = (i < Nn) ? deg[i] : 0;
  sm[t] = v;
  __syncthreads();
#pragma unroll
  for (int off = 1; off < 256; off <<= 1) {
    int add = (t >= off) ? sm[t - off] : 0;
    __syncthreads();
    sm[t] += add;
    __syncthreads();
  }
  if (t == 255) {
    atomicExch(&aggr[b], sm[255]);
    atomicExch(&flg[b], 1);
  }
  if (b == 0) {
    for (int j = t; j < nb; j += 256)
      while (atomicAdd(&flg[j], 0) == 0) __builtin_amdgcn_s_sleep(1);
    __syncthreads();
    int a = (t < nb) ? atomicAdd(&aggr[t], 0) : 0;
    __shared__ int sb[256];
    sb[t] = a;
    __syncthreads();
#pragma unroll
    for (int off = 1; off < 256; off <<= 1) {
      int add = (t >= off) ? sb[t - off] : 0;
      __syncthreads();
      sb[t] += add;
      __syncthreads();
    }
    if (t < nb) atomicExch(&incl[t], sb[t]);
    __syncthreads();
    if (t == 0) atomicExch(&flg[nb], 1);
    if (t == 0) s_prefix = 0;
  } else {
    if (t == 0) {
      while (atomicAdd(&flg[nb], 0) == 0) __builtin_amdgcn_s_sleep(8);
      s_prefix = atomicAdd(&incl[b - 1], 0);
    }
  }
  __syncthreads();
  int ex = s_prefix + sm[t] - v;
  if (i < Nn) {
    offs[i] = ex;
    pos[i] = ex;
    if (i == Nn - 1) offs[Nn] = ex + v;
  }
}

__global__ void fill_csr(const int* __restrict__ eidx, int* __restrict__ pos,
                         int* __restrict__ esrc, int E) {
  int e = blockIdx.x * blockDim.x + threadIdx.x;
  if (e < E) {
    int s = eidx[e];
    int d = eidx[e + E];
    int p = atomicAdd(&pos[d], 1);
    esrc[p] = s;
  }
}

// --------------- fused prep: zero (deg+flg) + cast x + transposes -----------
__global__ __launch_bounds__(256) void prep(
    int* __restrict__ zp, int zn,
    const float* __restrict__ x, unsigned short* __restrict__ xb, long long n4,
    const float* __restrict__ W1a, const float* __restrict__ W2a,
    const float* __restrict__ W1b, const float* __restrict__ W2b,
    unsigned short* __restrict__ w1t, unsigned short* __restrict__ w2t,
    unsigned short* __restrict__ w3t, unsigned short* __restrict__ w4t) {
  int zb = (zn + 255) >> 8;
  int b = blockIdx.x;
  int t = threadIdx.x;
  if (b < zb) {
    int i = b * 256 + t;
    if (i < zn) zp[i] = 0;
  } else if (b < zb + 768) {
    int i = (b - zb) * 256 + t;  // 0..196607
    const float* W;
    unsigned short* WT;
    int K, N, j;
    if (i < 32768) {            // W1a: 128x256
      W = W1a; WT = w1t; K = 128; N = 256; j = i;
    } else if (i < 98304) {     // W2a: 256x256
      W = W2a; WT = w2t; K = 256; N = 256; j = i - 32768;
    } else if (i < 163840) {    // W1b: 256x256
      W = W1b; WT = w3t; K = 256; N = 256; j = i - 98304;
    } else {                    // W2b: 256x128
      W = W2b; WT = w4t; K = 256; N = 128; j = i - 163840;
    }
    int k = j / N, n = j - k * N;
    WT[n * K + k] = f2bf(W[j]);
  } else {
    long long i = (long long)(b - zb - 768) * 256 + t;
    long long stride = (long long)(gridDim.x - zb - 768) * 256;
    for (; i < n4; i += stride) {
      float4 v = ((const float4*)x)[i];
      u16x4 o;
      o.x = f2bf(v.x); o.y = f2bf(v.y); o.z = f2bf(v.z); o.w = f2bf(v.w);
      ((u16x4*)xb)[i] = o;
    }
  }
}

// ------------------------- aggregation (R10) --------------------------------
__global__ __launch_bounds__(256) void agg_bf16_128(
    unsigned short* __restrict__ out, const unsigned short* __restrict__ xb,
    const int* __restrict__ offs, const int* __restrict__ esrc, int Nn) {
  int node = blockIdx.x * 4 + (threadIdx.x >> 6);
  if (node >= Nn) return;
  int lane = threadIdx.x & 63;
  int grp = lane >> 4, l16 = lane & 15;
  int beg = offs[node], end = offs[node + 1];
  int total = end - beg + 1;  // incl. self
  const unsigned short* xp = xb + l16 * 8;
  f32x2 acc[4] = {};
  for (int j0 = 0; j0 < total; j0 += 16) {
#pragma unroll
    for (int u = 0; u < 4; ++u) {
      int j = j0 + u * 4 + grp;
      int rv = esrc[beg + j - (j > 0)];
      long long row = (j > 0 && j < total) ? rv : node;
      float sel = (j < total) ? 1.f : 0.f;
      f32x2 fsel = {sel, sel};
      u32x4 w = *(const u32x4*)(xp + row * 128);
#pragma unroll
      for (int k = 0; k < 4; ++k) acc[k] += bfpair(w[k]) * fsel;
    }
  }
  float s[8];
#pragma unroll
  for (int k = 0; k < 4; ++k) { s[2 * k] = acc[k].x; s[2 * k + 1] = acc[k].y; }
#pragma unroll
  for (int k = 0; k < 8; ++k) s[k] += __shfl_xor(s[k], 16);
#pragma unroll
  for (int k = 0; k < 8; ++k) s[k] += __shfl_xor(s[k], 32);
  if (grp == 0) {
    u16x8 o;
#pragma unroll
    for (int k = 0; k < 8; ++k) o[k] = f2bf(s[k]);
    *(u16x8*)(out + (long long)node * 128 + l16 * 8) = o;
  }
}

__global__ __launch_bounds__(256) void agg_bf16_256(
    unsigned short* __restrict__ out, const unsigned short* __restrict__ h,
    const int* __restrict__ offs, const int* __restrict__ esrc, int Nn) {
  int node = blockIdx.x * 4 + (threadIdx.x >> 6);
  if (node >= Nn) return;
  int lane = threadIdx.x & 63;
  int grp = lane >> 5, l32 = lane & 31;
  int beg = offs[node], end = offs[node + 1];
  int total = end - beg + 1;  // incl. self
  const unsigned short* hp = h + l32 * 8;
  f32x2 acc[4] = {};
  for (int j0 = 0; j0 < total; j0 += 16) {
#pragma unroll
    for (int u = 0; u < 8; ++u) {
      int j = j0 + u * 2 + grp;
      int rv = esrc[beg + j - (j > 0)];
      long long row = (j > 0 && j < total) ? rv : node;
      float sel = (j < total) ? 1.f : 0.f;
      f32x2 fsel = {sel, sel};
      u32x4 w = *(const u32x4*)(hp + row * 256);
#pragma unroll
      for (int k = 0; k < 4; ++k) acc[k] += bfpair(w[k]) * fsel;
    }
  }
  float s[8];
#pragma unroll
  for (int k = 0; k < 4; ++k) { s[2 * k] = acc[k].x; s[2 * k + 1] = acc[k].y; }
#pragma unroll
  for (int k = 0; k < 8; ++k) s[k] += __shfl_xor(s[k], 32);
  if (grp == 0) {
    u16x8 o;
#pragma unroll
    for (int k = 0; k < 8; ++k) o[k] = f2bf(s[k]);
    *(u16x8*)(out + (long long)node * 256 + l32 * 8) = o;
  }
}

// ------------------- barrier-free fused MLP ---------------------------------
// C = relu?(relu(A@W1+b1)@W2+b2). A bf16 [M][K1]; BT1 bf16 [256][K1];
// BT2 bf16 [N2][256]. Block = 64 rows, 4 waves (wave w owns cols
// w*64..w*64+63 of stage1, w*(N2/4).. of stage2). A/B frags loaded straight
// from global (L2-hot) — no LDS staging, no k-loop barriers. Only Ts (64x264)
// in LDS; exactly one __syncthreads per block.
template <int K1, int N2, bool OUT_BF16>
__global__ __launch_bounds__(256) void mlp_nobar(
    const unsigned short* __restrict__ A,
    const unsigned short* __restrict__ BT1, const float* __restrict__ b1,
    const unsigned short* __restrict__ BT2, const float* __restrict__ b2,
    void* __restrict__ Cout, int M) {
  constexpr int LDT = 264;
  __shared__ unsigned short Ts[64 * LDT];  // 33.8 KB
  const int wave = threadIdx.x >> 6, lane = threadIdx.x & 63;
  const int quad = lane >> 4, l16 = lane & 15;
  const int rowBase = blockIdx.x * 64;

  // ---- stage 1: T = relu(A @ W1 + b1), all frags from global ----
  const unsigned short* aptr[4];
#pragma unroll
  for (int mi = 0; mi < 4; ++mi) {
    long long r = min(rowBase + mi * 16 + l16, M - 1);
    aptr[mi] = A + r * K1 + quad * 8;
  }
  const unsigned short* bptr1 =
      BT1 + (long long)(wave * 64 + l16) * K1 + quad * 8;

  f32x4 acc1[4][4] = {};
#pragma unroll 2
  for (int kk = 0; kk < K1 / 32; ++kk) {
    bf16x8 af[4], bf[4];
#pragma unroll
    for (int mi = 0; mi < 4; ++mi)
      af[mi] = *(const bf16x8*)(aptr[mi] + kk * 32);
#pragma unroll
    for (int ni = 0; ni < 4; ++ni)
      bf[ni] = *(const bf16x8*)(bptr1 + (long long)ni * 16 * K1 + kk * 32);
#pragma unroll
    for (int mi = 0; mi < 4; ++mi)
#pragma unroll
      for (int ni = 0; ni < 4; ++ni)
        acc1[mi][ni] = __builtin_amdgcn_mfma_f32_16x16x32_bf16(
            af[mi], bf[ni], acc1[mi][ni], 0, 0, 0);
  }
  // epilogue 1 -> Ts
#pragma unroll
  for (int ni = 0; ni < 4; ++ni) {
    int col = wave * 64 + ni * 16 + l16;
    float bv = b1[col];
#pragma unroll
    for (int mi = 0; mi < 4; ++mi)
#pragma unroll
      for (int r = 0; r < 4; ++r) {
        int row = mi * 16 + quad * 4 + r;
        Ts[row * LDT + col] = f2bf(fmaxf(acc1[mi][ni][r] + bv, 0.f));
      }
  }
  __syncthreads();  // the only block barrier

  // ---- stage 2: C = Ts @ W2 + b2; B from global, A from LDS ----
  constexpr int NI2 = N2 / 64;
  const int wcol = wave * (N2 / 4);
  const unsigned short* bptr2 =
      BT2 + (long long)(wcol + l16) * 256 + quad * 8;
  f32x4 acc2[4][NI2] = {};
#pragma unroll 2
  for (int kk = 0; kk < 8; ++kk) {
    bf16x8 af[4], bf[NI2];
#pragma unroll
    for (int mi = 0; mi < 4; ++mi)
      af[mi] = *(const bf16x8*)(Ts + (mi * 16 + l16) * LDT + kk * 32 + quad * 8);
#pragma unroll
    for (int ni = 0; ni < NI2; ++ni)
      bf[ni] = *(const bf16x8*)(bptr2 + (long long)ni * 16 * 256 + kk * 32);
#pragma unroll
    for (int mi = 0; mi < 4; ++mi)
#pragma unroll
      for (int ni = 0; ni < NI2; ++ni)
        acc2[mi][ni] = __builtin_amdgcn_mfma_f32_16x16x32_bf16(
            af[mi], bf[ni], acc2[mi][ni], 0, 0, 0);
  }
  // epilogue 2
#pragma unroll
  for (int ni = 0; ni < NI2; ++ni) {
    int col = wcol + ni * 16 + l16;
    float bv = b2[col];
#pragma unroll
    for (int mi = 0; mi < 4; ++mi)
#pragma unroll
      for (int r = 0; r < 4; ++r) {
        int row = rowBase + mi * 16 + quad * 4 + r;
        if (row < M) {
          float o = acc2[mi][ni][r] + bv;
          if (OUT_BF16)
            ((unsigned short*)Cout)[(long long)row * N2 + col] = f2bf(fmaxf(o, 0.f));
          else
            ((float*)Cout)[(long long)row * N2 + col] = o;
        }
      }
  }
}

// ---------------------------------------------------------------------------
extern "C" void kernel_launch(void* const* d_in, const int* in_sizes, int n_in,
                              void* d_out, int out_size, void* d_ws, size_t ws_size,
                              hipStream_t stream) {
  const float* x   = (const float*)d_in[0];
  const float* W1a = (const float*)d_in[1];
  const float* b1a = (const float*)d_in[2];
  const float* W2a = (const float*)d_in[3];
  const float* b2a = (const float*)d_in[4];
  const float* W1b = (const float*)d_in[5];
  const float* b1b = (const float*)d_in[6];
  const float* W2b = (const float*)d_in[7];
  const float* b2b = (const float*)d_in[8];
  const int*   ei  = (const int*)d_in[9];  // [2,E]: row0=src, row1=dst

  const int Nn = in_sizes[0] / 128;  // 50000
  const int E  = in_sizes[9] / 2;    // 600000
  float* out = (float*)d_out;

  const int nb = (Nn + 255) / 256;  // 196 scan blocks

  // workspace
  unsigned short* h   = (unsigned short*)d_ws;     // N*256 bf16
  unsigned short* g0  = h  + (size_t)Nn * 256;     // N*128
  unsigned short* g1  = g0 + (size_t)Nn * 128;     // N*256
  unsigned short* xb  = g1 + (size_t)Nn * 256;     // N*128
  unsigned short* w1t = xb + (size_t)Nn * 128;     // 256*128
  unsigned short* w2t = w1t + 256 * 128;           // 256*256
  unsigned short* w3t = w2t + 256 * 256;           // 256*256
  unsigned short* w4t = w3t + 256 * 256;           // 128*256
  int* deg  = (int*)(w4t + 128 * 256);  // Nn
  int* flg  = deg + Nn;                 // nb+1 (zeroed with deg by prep)
  int* aggr = flg + nb + 1;             // nb
  int* incl = aggr + nb;                // nb
  int* offs = incl + nb;                // Nn+1
  int* pos  = offs + Nn + 1;            // Nn
  int* esrc = pos + Nn;                 // E (+16 int overshoot pad into ws)

  dim3 blk(256);
  int zn = Nn + nb + 1;  // deg + flg zeroed together (contiguous)
  int zb = (zn + 255) / 256;

  // 1) prep
  prep<<<zb + 768 + 2048, blk, 0, stream>>>(deg, zn, x, xb,
                                            (long long)Nn * 128 / 4,
                                            W1a, W2a, W1b, W2b,
                                            w1t, w2t, w3t, w4t);
  // 2-4) CSR build
  hist<<<(E + 255) / 256, blk, 0, stream>>>(ei, deg, E);
  scan_all<<<nb, blk, 0, stream>>>(deg, offs, pos, aggr, incl, flg, Nn, nb);
  fill_csr<<<(E + 255) / 256, blk, 0, stream>>>(ei, pos, esrc, E);

  int aggBlocks = (Nn + 3) / 4;
  int mlpBlocks = (Nn + 63) / 64;  // 782

  // 5-6) layer 0
  agg_bf16_128<<<aggBlocks, blk, 0, stream>>>(g0, xb, offs, esrc, Nn);
  mlp_nobar<128, 256, true><<<mlpBlocks, blk, 0, stream>>>(
      g0, w1t, b1a, w2t, b2a, h, Nn);
  // 7-8) layer 1
  agg_bf16_256<<<aggBlocks, blk, 0, stream>>>(g1, h, offs, esrc, Nn);
  mlp_nobar<256, 128, false><<<mlpBlocks, blk, 0, stream>>>(
      g1, w3t, b1b, w4t, b2b, out, Nn);
}